// Round 6
// baseline (150.017 us; speedup 1.0000x reference)
//
#include <hip/hip_runtime.h>

#define NB   500000   // B: rule neurons
#define NW   8        // W: weights per rule
#define ND   16       // D: per-neuron dim

// fast tanh: 1 - 2/(exp(2x)+1); exact saturation at +-inf, ~1e-6 abs err
__device__ __forceinline__ float fast_tanh(float x) {
    float e = __expf(2.0f * x);                       // v_exp_f32 path
    return 1.0f - 2.0f * __builtin_amdgcn_rcpf(e + 1.0f);
}

// 4 threads per neuron b; thread (b, dq) owns float4 dq of the D=16 row.
// - out store: 16B/lane fully coalesced
// - gather: 4 consecutive lanes read one contiguous 64B values row
// - idx load: broadcast within each 4-lane group
__global__ __launch_bounds__(256) void wrl_kernel(
    const float* __restrict__ values,   // [N_SRC, 16]
    const float* __restrict__ weights,  // [8, 16]
    const int*   __restrict__ indices,  // [8, B]
    float* __restrict__ out)            // [B, 16]
{
    const int tid = blockIdx.x * 256 + threadIdx.x;
    if (tid >= NB * 4) return;
    const int b  = tid >> 2;
    const int dq = tid & 3;

    // weights into registers: 8 x float4 (broadcast loads, L1-resident)
    float4 wreg[NW];
#pragma unroll
    for (int w = 0; w < NW; ++w)
        wreg[w] = *reinterpret_cast<const float4*>(weights + w * ND + dq * 4);

    // issue all 8 index loads up front (latency overlap)
    int idx[NW];
#pragma unroll
    for (int w = 0; w < NW; ++w)
        idx[w] = indices[w * NB + b];

    float4 acc = make_float4(0.f, 0.f, 0.f, 0.f);
#pragma unroll
    for (int w = 0; w < NW; ++w) {
        const float4 v = *reinterpret_cast<const float4*>(
            values + (size_t)idx[w] * ND + dq * 4);
        acc.x += v.x * wreg[w].x;
        acc.y += v.y * wreg[w].y;
        acc.z += v.z * wreg[w].z;
        acc.w += v.w * wreg[w].w;
    }

    float4 o;
    o.x = fast_tanh(acc.x);
    o.y = fast_tanh(acc.y);
    o.z = fast_tanh(acc.z);
    o.w = fast_tanh(acc.w);
    *reinterpret_cast<float4*>(out + (size_t)b * ND + dq * 4) = o;
}

extern "C" void kernel_launch(void* const* d_in, const int* in_sizes, int n_in,
                              void* d_out, int out_size, void* d_ws, size_t ws_size,
                              hipStream_t stream) {
    const float* values  = (const float*)d_in[0];
    const float* weights = (const float*)d_in[1];
    const int*   indices = (const int*)d_in[2];
    float* out = (float*)d_out;

    const int total  = NB * 4;                 // 2M threads
    const int blocks = (total + 255) / 256;    // 7813
    wrl_kernel<<<blocks, 256, 0, stream>>>(values, weights, indices, out);
}